// Round 18
// baseline (230.818 us; speedup 1.0000x reference)
//
#include <hip/hip_runtime.h>
#include <hip/hip_bf16.h>
#include <cmath>

using u16 = unsigned short;
typedef __bf16 bf16x8 __attribute__((ext_vector_type(8)));
typedef __bf16 bf16x2 __attribute__((ext_vector_type(2)));
typedef unsigned short u16x8 __attribute__((ext_vector_type(8)));
typedef float f32x4 __attribute__((ext_vector_type(4)));

#define SEQ 4096
#define DM 768
#define NH 12
#define HD 64
#define HID 3072

__device__ __forceinline__ u16 f2bf(float f) {
    union { float f; unsigned u; } v; v.f = f;
    unsigned r = v.u + 0x7fffu + ((v.u >> 16) & 1u);
    return (u16)(r >> 16);
}

__device__ __forceinline__ unsigned pack_bf16(float a, float b) {
    union { bf16x2 v; unsigned u; } c;
    c.v[0] = (__bf16)a; c.v[1] = (__bf16)b;
    return c.u;
}

// exact-gelu via A&S 7.1.26 erf poly (|eps|<=1.5e-7)
__device__ __forceinline__ float gelu_exact(float v) {
    float z = fabsf(v) * 0.70710678118654752f;
    float t = __builtin_amdgcn_rcpf(__builtin_fmaf(0.3275911f, z, 1.0f));
    float p = t * __builtin_fmaf(t, __builtin_fmaf(t, __builtin_fmaf(t,
                __builtin_fmaf(t, 1.061405429f, -1.453152027f),
                1.421413741f), -0.284496736f), 0.254829592f);
    float e = __builtin_amdgcn_exp2f(-z * z * 1.44269504088896341f);
    float erfv = __builtin_fmaf(-p, e, 1.0f);
    erfv = (v < 0.0f) ? -erfv : erfv;
    return 0.5f * v * (1.0f + erfv);
}

// XOR swizzle, 64-u16 rows (8 chunks of 16B): chunk ^= row&7
__device__ __forceinline__ int swz64(int row, int k) {
    return (row << 6) | ((((k >> 3) ^ row) & 7) << 3) | (k & 7);
}
// XOR swizzle, 128-u16 rows (16 chunks of 16B): chunk ^= row&15
__device__ __forceinline__ int swz128(int row, int k) {
    return (row << 7) | ((((k >> 3) ^ row) & 15) << 3) | (k & 7);
}

// ---------------- transpose f32 [K][N] -> bf16 [N][K] ----------------
__global__ void transpose_to_bf16(const float* __restrict__ W, u16* __restrict__ Wt,
                                  int K, int N) {
    __shared__ float tile[32][33];
    int kb = blockIdx.y * 32, nb = blockIdx.x * 32;
    int tx = threadIdx.x, ty = threadIdx.y; // 32 x 8
#pragma unroll
    for (int i = 0; i < 32; i += 8)
        tile[ty + i][tx] = W[(size_t)(kb + ty + i) * N + nb + tx];
    __syncthreads();
#pragma unroll
    for (int i = 0; i < 32; i += 8)
        Wt[(size_t)(nb + ty + i) * K + kb + tx] = f2bf(tile[tx][ty + i]);
}

// ---------------- LayerNorm: f32 [4096][768] -> bf16 ----------------
__global__ __launch_bounds__(256) void ln_kernel(const float* __restrict__ x,
                                                 const float* __restrict__ g,
                                                 const float* __restrict__ b,
                                                 u16* __restrict__ y) {
    int row = blockIdx.x, t = threadIdx.x;
    const float* xr = x + (size_t)row * DM;
    float v0 = xr[t], v1 = xr[t + 256], v2 = xr[t + 512];
    float s = v0 + v1 + v2;
#pragma unroll
    for (int m = 32; m; m >>= 1) s += __shfl_xor(s, m);
    __shared__ float red[4], red2[4];
    int wid = t >> 6, lane = t & 63;
    if (lane == 0) red[wid] = s;
    __syncthreads();
    float mean = (red[0] + red[1] + red[2] + red[3]) * (1.0f / DM);
    float d0 = v0 - mean, d1 = v1 - mean, d2 = v2 - mean;
    float q = d0 * d0 + d1 * d1 + d2 * d2;
#pragma unroll
    for (int m = 32; m; m >>= 1) q += __shfl_xor(q, m);
    if (lane == 0) red2[wid] = q;
    __syncthreads();
    float var = (red2[0] + red2[1] + red2[2] + red2[3]) * (1.0f / DM);
    float rstd = rsqrtf(var + 1e-5f);
    y[(size_t)row * DM + t]       = f2bf(d0 * rstd * g[t]       + b[t]);
    y[(size_t)row * DM + t + 256] = f2bf(d1 * rstd * g[t + 256] + b[t + 256]);
    y[(size_t)row * DM + t + 512] = f2bf(d2 * rstd * g[t + 512] + b[t + 512]);
}

// ---------------- GEMM: A[M][K] bf16 x Bt[N][K] bf16, TMxTN tile ----------------
// r9/r15 schedule (reg-staged, dbuf, one barrier per K-step).
// TN=128: 4 waves side-by-side (wrow=0, MF=4, NF=2)
// TN=64:  2x2 wave quadrants of 32x32 (MF=2, NF=2)  [max blocks/CU — proven lever]
template<int TM, int TN>
__global__ __launch_bounds__(256) void gemm_bf16(
    const u16* __restrict__ A, const u16* __restrict__ Bt,
    const float* __restrict__ bias, const float* __restrict__ resid,
    float* __restrict__ outF, u16* __restrict__ outB,
    int M, int N, int K, int gelu) {
    constexpr int AP = TM / 32;              // A staging rounds
    constexpr int BP = TN / 32;              // B staging rounds
    constexpr int MF = (TN == 128) ? 4 : 2;  // M frags per wave
    constexpr int NF = 2;                    // N frags per wave
    __shared__ __align__(16) u16 As[2][TM * 64];
    __shared__ __align__(16) u16 Bs[2][TN * 64];
    int tid = threadIdx.x;
    int lane = tid & 63, wid = tid >> 6;
    int lr = lane & 15, hi = lane >> 4;
    int wrow = (TN == 128) ? 0 : (wid >> 1) * 32;
    int wcol = (TN == 128) ? wid * 32 : (wid & 1) * 32;
    int m0 = blockIdx.y * TM, n0 = blockIdx.x * TN;

    f32x4 acc[MF][NF] = {};
    int srow = tid >> 3;          // 0..31
    int sk = (tid & 7) << 3;      // 0..56
    const u16* Ag = A + (size_t)(m0 + srow) * K + sk;
    const u16* Bg = Bt + (size_t)(n0 + srow) * K + sk;

    u16x8 ar[AP], br[BP];
    auto LOAD = [&](int kt) {
#pragma unroll
        for (int p = 0; p < AP; ++p)
            ar[p] = *reinterpret_cast<const u16x8*>(Ag + (size_t)p * 32 * K + kt);
#pragma unroll
        for (int p = 0; p < BP; ++p)
            br[p] = *reinterpret_cast<const u16x8*>(Bg + (size_t)p * 32 * K + kt);
    };
    auto WRITE = [&](int buf) {
#pragma unroll
        for (int p = 0; p < AP; ++p)
            *reinterpret_cast<u16x8*>(&As[buf][swz64(srow + p * 32, sk)]) = ar[p];
#pragma unroll
        for (int p = 0; p < BP; ++p)
            *reinterpret_cast<u16x8*>(&Bs[buf][swz64(srow + p * 32, sk)]) = br[p];
    };

    int NT = K >> 6;
    LOAD(0);
    WRITE(0);
#pragma unroll 2
    for (int t = 0; t < NT; ++t) {
        if (t + 1 < NT) LOAD((t + 1) << 6);
        __syncthreads();
        const u16* as = &As[t & 1][0];
        const u16* bs = &Bs[t & 1][0];
#pragma unroll
        for (int ks = 0; ks < 2; ++ks) {
            bf16x8 af[MF], bfr[NF];
#pragma unroll
            for (int m = 0; m < MF; ++m)
                af[m] = *reinterpret_cast<const bf16x8*>(&as[swz64(wrow + m * 16 + lr, ks * 32 + hi * 8)]);
#pragma unroll
            for (int n = 0; n < NF; ++n)
                bfr[n] = *reinterpret_cast<const bf16x8*>(&bs[swz64(wcol + n * 16 + lr, ks * 32 + hi * 8)]);
            __builtin_amdgcn_s_setprio(1);
#pragma unroll
            for (int m = 0; m < MF; ++m)
#pragma unroll
                for (int n = 0; n < NF; ++n)
                    acc[m][n] = __builtin_amdgcn_mfma_f32_16x16x32_bf16(af[m], bfr[n], acc[m][n], 0, 0, 0);
            __builtin_amdgcn_s_setprio(0);
        }
        if (t + 1 < NT) WRITE((t + 1) & 1);
    }
#pragma unroll
    for (int m = 0; m < MF; ++m) {
#pragma unroll
        for (int n = 0; n < NF; ++n) {
            int col = n0 + wcol + n * 16 + lr;
            float bv = bias[col];
#pragma unroll
            for (int r = 0; r < 4; ++r) {
                int row = m0 + wrow + m * 16 + hi * 4 + r;
                float v = acc[m][n][r] + bv;
                if (gelu) v = gelu_exact(v);
                if (resid) v += resid[(size_t)row * N + col];
                if (outF) outF[(size_t)row * N + col] = v;
                if (outB) outB[(size_t)row * N + col] = f2bf(v);
            }
        }
    }
}

// ---------------- flash attention (r15 best: QBLK=64, KVBLK=128 dbuf, 256 thr) ----------------
__global__ __launch_bounds__(256, 2) void attn_kernel(const u16* __restrict__ qkv,
                                                      u16* __restrict__ attn) {
    __shared__ __align__(16) u16 Ks[2][128 * 64];   // [kv][hd], swz64
    __shared__ __align__(16) u16 Vt[2][64 * 128];   // [hd][kv], swz128
    int tid = threadIdx.x;
    int lane = tid & 63, w = tid >> 6;
    int lr = lane & 15, hi = lane >> 4;
    int upper = hi >> 1;
    const float SCL = 0.125f * 1.44269504088896340736f;  // 1/sqrt(64) * log2(e)

    int bid = blockIdx.x;
    int h = bid % NH;
    int qb = (SEQ / 64 - 1) - bid / NH;   // LPT: biggest work first

    int qrow = qb * 64 + w * 16 + lr;
    bf16x8 qf[2];
#pragma unroll
    for (int ks = 0; ks < 2; ++ks)
        qf[ks] = *reinterpret_cast<const bf16x8*>(&qkv[(size_t)qrow * 2304 + h * 192 + ks * 32 + hi * 8]);

    f32x4 acc[4] = {};
    float m_run = -INFINITY, l_run = 0.0f;   // m_run in log2 domain

    // staging lanes
    int skvr = tid >> 3;            // K: row 0..31 (+p*32)
    int skc = (tid & 7) << 3;       // K: col
    int svd = tid & 63;             // V: head-dim
    int svk = (tid >> 6) * 32;      // V: kv base
    u16x8 kr[4], vr[4];

    auto LOADKV = [&](int kb) {
#pragma unroll
        for (int p = 0; p < 4; ++p)
            kr[p] = *reinterpret_cast<const u16x8*>(
                &qkv[(size_t)(kb * 128 + skvr + p * 32) * 2304 + h * 192 + 64 + skc]);
        const u16* vb = &qkv[(size_t)(kb * 128 + svk) * 2304 + h * 192 + 128 + svd];
#pragma unroll
        for (int g = 0; g < 4; ++g)
#pragma unroll
            for (int j = 0; j < 8; ++j)
                vr[g][j] = vb[(size_t)(g * 8 + j) * 2304];
    };
    auto WRITEKV = [&](int buf) {
#pragma unroll
        for (int p = 0; p < 4; ++p)
            *reinterpret_cast<u16x8*>(&Ks[buf][swz64(skvr + p * 32, skc)]) = kr[p];
#pragma unroll
        for (int g = 0; g < 4; ++g)
            *reinterpret_cast<u16x8*>(&Vt[buf][swz128(svd, svk + g * 8)]) = vr[g];
    };

    int nt = (qb * 64 + 64 + 127) >> 7;   // causal tile count (KVBLK=128)
    LOADKV(0);
    WRITEKV(0);
    for (int kb = 0; kb < nt; ++kb) {
        if (kb + 1 < nt) LOADKV(kb + 1);
        __syncthreads();
        const u16* ksb = &Ks[kb & 1][0];
        const u16* vtb = &Vt[kb & 1][0];

        // ---- S^T = K x Q^T ----
        f32x4 s[8] = {};
        __builtin_amdgcn_s_setprio(1);
#pragma unroll
        for (int ks = 0; ks < 2; ++ks) {
#pragma unroll
            for (int n = 0; n < 8; ++n) {
                bf16x8 kf = *reinterpret_cast<const bf16x8*>(&ksb[swz64(n * 16 + lr, ks * 32 + hi * 8)]);
                s[n] = __builtin_amdgcn_mfma_f32_16x16x32_bf16(kf, qf[ks], s[n], 0, 0, 0);
            }
        }
        __builtin_amdgcn_s_setprio(0);
        // ---- causal mask: only the diagonal tile needs it ----
        float sv[8][4];
#pragma unroll
        for (int n = 0; n < 8; ++n) {
            sv[n][0] = s[n][0]; sv[n][1] = s[n][1]; sv[n][2] = s[n][2]; sv[n][3] = s[n][3];
        }
        if (kb == nt - 1) {
#pragma unroll
            for (int n = 0; n < 8; ++n)
#pragma unroll
                for (int r = 0; r < 4; ++r) {
                    int kv = kb * 128 + n * 16 + hi * 4 + r;
                    if (kv > qrow) sv[n][r] = -3.0e38f;
                }
        }
        // ---- online softmax, log2 domain, defer-max (THR=8) ----
        float t8[8];
#pragma unroll
        for (int n = 0; n < 8; ++n)
            t8[n] = fmaxf(fmaxf(sv[n][0], sv[n][1]), fmaxf(sv[n][2], sv[n][3]));
        float mx = fmaxf(fmaxf(fmaxf(t8[0], t8[1]), fmaxf(t8[2], t8[3])),
                         fmaxf(fmaxf(t8[4], t8[5]), fmaxf(t8[6], t8[7])));
        mx = fmaxf(mx, __shfl_xor(mx, 16));
        mx = fmaxf(mx, __shfl_xor(mx, 32));
        float mxs = mx * SCL;
        if (!__all(mxs <= m_run + 8.0f)) {
            float mnew = fmaxf(m_run, mxs);
            float alpha = __builtin_amdgcn_exp2f(m_run - mnew);
            l_run *= alpha;
#pragma unroll
            for (int n2 = 0; n2 < 4; ++n2)
#pragma unroll
                for (int r = 0; r < 4; ++r) acc[n2][r] *= alpha;
            m_run = mnew;
        }
        float rs = 0.0f;
#pragma unroll
        for (int n = 0; n < 8; ++n) {
            float p0 = __builtin_amdgcn_exp2f(__builtin_fmaf(sv[n][0], SCL, -m_run));
            float p1 = __builtin_amdgcn_exp2f(__builtin_fmaf(sv[n][1], SCL, -m_run));
            float p2 = __builtin_amdgcn_exp2f(__builtin_fmaf(sv[n][2], SCL, -m_run));
            float p3 = __builtin_amdgcn_exp2f(__builtin_fmaf(sv[n][3], SCL, -m_run));
            sv[n][0] = p0; sv[n][1] = p1; sv[n][2] = p2; sv[n][3] = p3;
            rs += (p0 + p1) + (p2 + p3);
        }
        rs += __shfl_xor(rs, 16);
        rs += __shfl_xor(rs, 32);
        l_run += rs;

        // ---- pack P^T to bf16 pairs in-register ----
        unsigned pk0[8], pk1[8];
#pragma unroll
        for (int n = 0; n < 8; ++n) {
            pk0[n] = pack_bf16(sv[n][0], sv[n][1]);
            pk1[n] = pack_bf16(sv[n][2], sv[n][3]);
        }
        // ---- build B-fragments of P^T via cross-lane exchange, then PV ----
        int src0 = lr + ((hi & 1) << 5);
        int src1 = src0 + 16;
#pragma unroll
        for (int ks = 0; ks < 4; ++ks) {
            union { unsigned w4[4]; bf16x8 v; } pf;
            {
                unsigned a0 = __shfl(pk0[2 * ks], src0), b0 = __shfl(pk0[2 * ks + 1], src0);
                unsigned a1 = __shfl(pk1[2 * ks], src0), b1 = __shfl(pk1[2 * ks + 1], src0);
                unsigned a2 = __shfl(pk0[2 * ks], src1), b2 = __shfl(pk0[2 * ks + 1], src1);
                unsigned a3 = __shfl(pk1[2 * ks], src1), b3 = __shfl(pk1[2 * ks + 1], src1);
                pf.w4[0] = upper ? b0 : a0;
                pf.w4[1] = upper ? b1 : a1;
                pf.w4[2] = upper ? b2 : a2;
                pf.w4[3] = upper ? b3 : a3;
            }
            __builtin_amdgcn_s_setprio(1);
#pragma unroll
            for (int n2 = 0; n2 < 4; ++n2) {
                bf16x8 vf = *reinterpret_cast<const bf16x8*>(&vtb[swz128(n2 * 16 + lr, ks * 32 + hi * 8)]);
                acc[n2] = __builtin_amdgcn_mfma_f32_16x16x32_bf16(vf, pf.v, acc[n2], 0, 0, 0);
            }
            __builtin_amdgcn_s_setprio(0);
        }
        if (kb + 1 < nt) WRITEKV((kb + 1) & 1);
    }
    // ---- store O^T -> attn[q][h*64+d], normalized ----
    float inv = 1.0f / l_run;
#pragma unroll
    for (int n2 = 0; n2 < 4; ++n2) {
#pragma unroll
        for (int r = 0; r < 4; ++r) {
            int dcol = h * 64 + n2 * 16 + hi * 4 + r;
            attn[(size_t)qrow * DM + dcol] = f2bf(acc[n2][r] * inv);
        }
    }
}

extern "C" void kernel_launch(void* const* d_in, const int* in_sizes, int n_in,
                              void* d_out, int out_size, void* d_ws, size_t ws_size,
                              hipStream_t stream) {
    const float* x      = (const float*)d_in[0];
    const float* gamma1 = (const float*)d_in[1];
    const float* beta1  = (const float*)d_in[2];
    const float* Wqkv   = (const float*)d_in[3];
    const float* bqkv   = (const float*)d_in[4];
    const float* Wo     = (const float*)d_in[5];
    const float* bo     = (const float*)d_in[6];
    const float* gamma2 = (const float*)d_in[7];
    const float* beta2  = (const float*)d_in[8];
    const float* W1     = (const float*)d_in[9];
    const float* b1     = (const float*)d_in[10];
    const float* W2     = (const float*)d_in[11];
    const float* b2     = (const float*)d_in[12];

    char* ws = (char*)d_ws;
    size_t off = 0;
    u16* WqkvT = (u16*)(ws + off); off += (size_t)2304 * 768 * 2;
    u16* WoT   = (u16*)(ws + off); off += (size_t)768 * 768 * 2;
    u16* W1T   = (u16*)(ws + off); off += (size_t)3072 * 768 * 2;
    u16* W2T   = (u16*)(ws + off); off += (size_t)768 * 3072 * 2;
    u16* B1    = (u16*)(ws + off); off += (size_t)SEQ * DM * 2;      // y1 / attn / y2
    u16* Q     = (u16*)(ws + off); off += (size_t)SEQ * HID * 2;     // qkv, then h
    float* x1  = (float*)(ws + off); off += (size_t)SEQ * DM * 4;

    dim3 tb(32, 8);
    transpose_to_bf16<<<dim3(2304 / 32, 768 / 32), tb, 0, stream>>>(Wqkv, WqkvT, 768, 2304);
    transpose_to_bf16<<<dim3(768 / 32, 768 / 32), tb, 0, stream>>>(Wo, WoT, 768, 768);
    transpose_to_bf16<<<dim3(3072 / 32, 768 / 32), tb, 0, stream>>>(W1, W1T, 768, 3072);
    transpose_to_bf16<<<dim3(768 / 32, 3072 / 32), tb, 0, stream>>>(W2, W2T, 3072, 768);

    ln_kernel<<<SEQ, 256, 0, stream>>>(x, gamma1, beta1, B1);
    gemm_bf16<64, 64><<<dim3(2304 / 64, SEQ / 64), 256, 0, stream>>>(B1, WqkvT, bqkv, nullptr, nullptr, Q, SEQ, 2304, 768, 0);
    attn_kernel<<<dim3((SEQ / 64) * NH), 256, 0, stream>>>(Q, B1);
    gemm_bf16<64, 64><<<dim3(768 / 64, SEQ / 64), 256, 0, stream>>>(B1, WoT, bo, x, x1, nullptr, SEQ, 768, 768, 0);
    ln_kernel<<<SEQ, 256, 0, stream>>>(x1, gamma2, beta2, B1);
    gemm_bf16<64, 64><<<dim3(3072 / 64, SEQ / 64), 256, 0, stream>>>(B1, W1T, b1, nullptr, nullptr, Q, SEQ, 3072, 768, 1);
    gemm_bf16<64, 64><<<dim3(768 / 64, SEQ / 64), 256, 0, stream>>>(Q, W2T, b2, x1, (float*)d_out, nullptr, SEQ, 768, 3072, 0);
}

// Round 19
// 215.964 us; speedup vs baseline: 1.0688x; 1.0688x over previous
//
#include <hip/hip_runtime.h>
#include <hip/hip_bf16.h>
#include <cmath>

using u16 = unsigned short;
typedef __bf16 bf16x8 __attribute__((ext_vector_type(8)));
typedef __bf16 bf16x2 __attribute__((ext_vector_type(2)));
typedef unsigned short u16x8 __attribute__((ext_vector_type(8)));
typedef float f32x4 __attribute__((ext_vector_type(4)));

#define SEQ 4096
#define DM 768
#define NH 12
#define HD 64
#define HID 3072

__device__ __forceinline__ u16 f2bf(float f) {
    union { float f; unsigned u; } v; v.f = f;
    unsigned r = v.u + 0x7fffu + ((v.u >> 16) & 1u);
    return (u16)(r >> 16);
}

__device__ __forceinline__ unsigned pack_bf16(float a, float b) {
    union { bf16x2 v; unsigned u; } c;
    c.v[0] = (__bf16)a; c.v[1] = (__bf16)b;
    return c.u;
}

// exact-gelu via A&S 7.1.26 erf poly (|eps|<=1.5e-7)
__device__ __forceinline__ float gelu_exact(float v) {
    float z = fabsf(v) * 0.70710678118654752f;
    float t = __builtin_amdgcn_rcpf(__builtin_fmaf(0.3275911f, z, 1.0f));
    float p = t * __builtin_fmaf(t, __builtin_fmaf(t, __builtin_fmaf(t,
                __builtin_fmaf(t, 1.061405429f, -1.453152027f),
                1.421413741f), -0.284496736f), 0.254829592f);
    float e = __builtin_amdgcn_exp2f(-z * z * 1.44269504088896341f);
    float erfv = __builtin_fmaf(-p, e, 1.0f);
    erfv = (v < 0.0f) ? -erfv : erfv;
    return 0.5f * v * (1.0f + erfv);
}

// XOR swizzle, 64-u16 rows (8 chunks of 16B): chunk ^= row&7
__device__ __forceinline__ int swz64(int row, int k) {
    return (row << 6) | ((((k >> 3) ^ row) & 7) << 3) | (k & 7);
}
// XOR swizzle, 128-u16 rows (16 chunks of 16B): chunk ^= row&15
__device__ __forceinline__ int swz128(int row, int k) {
    return (row << 7) | ((((k >> 3) ^ row) & 15) << 3) | (k & 7);
}

__device__ __forceinline__ void ln_row(const float* __restrict__ xr,
                                       const float* __restrict__ g,
                                       const float* __restrict__ b,
                                       u16* __restrict__ yr, int t) {
    float v0 = xr[t], v1 = xr[t + 256], v2 = xr[t + 512];
    float s = v0 + v1 + v2;
#pragma unroll
    for (int m = 32; m; m >>= 1) s += __shfl_xor(s, m);
    __shared__ float red[4], red2[4];
    int wid = t >> 6, lane = t & 63;
    if (lane == 0) red[wid] = s;
    __syncthreads();
    float mean = (red[0] + red[1] + red[2] + red[3]) * (1.0f / DM);
    float d0 = v0 - mean, d1 = v1 - mean, d2 = v2 - mean;
    float q = d0 * d0 + d1 * d1 + d2 * d2;
#pragma unroll
    for (int m = 32; m; m >>= 1) q += __shfl_xor(q, m);
    if (lane == 0) red2[wid] = q;
    __syncthreads();
    float var = (red2[0] + red2[1] + red2[2] + red2[3]) * (1.0f / DM);
    float rstd = rsqrtf(var + 1e-5f);
    yr[t]       = f2bf(d0 * rstd * g[t]       + b[t]);
    yr[t + 256] = f2bf(d1 * rstd * g[t + 256] + b[t + 256]);
    yr[t + 512] = f2bf(d2 * rstd * g[t + 512] + b[t + 512]);
}

// ---------------- fused prep: 4 weight transposes + LN1, one launch ----------------
// blocks [0,1728): WqkvT | [1728,2304): WoT | [2304,4608): W1T | [4608,6912): W2T
// blocks [6912,11008): LN1 rows. Per-block uniform role -> no divergence.
__global__ __launch_bounds__(256) void prep_kernel(
    const float* __restrict__ x, const float* __restrict__ g1, const float* __restrict__ b1,
    const float* __restrict__ Wqkv, const float* __restrict__ Wo,
    const float* __restrict__ W1, const float* __restrict__ W2,
    u16* __restrict__ WqkvT, u16* __restrict__ WoT,
    u16* __restrict__ W1T, u16* __restrict__ W2T, u16* __restrict__ y) {
    int bid = blockIdx.x;
    if (bid < 6912) {
        const float* W; u16* Wt; int K, N, ntx, b;
        if (bid < 1728)      { W = Wqkv; Wt = WqkvT; K = 768;  N = 2304; ntx = 72; b = bid; }
        else if (bid < 2304) { W = Wo;   Wt = WoT;   K = 768;  N = 768;  ntx = 24; b = bid - 1728; }
        else if (bid < 4608) { W = W1;   Wt = W1T;   K = 768;  N = 3072; ntx = 96; b = bid - 2304; }
        else                 { W = W2;   Wt = W2T;   K = 3072; N = 768;  ntx = 24; b = bid - 4608; }
        int nb = (b % ntx) * 32, kb = (b / ntx) * 32;
        __shared__ float tile[32][33];
        int tx = threadIdx.x & 31, ty = threadIdx.x >> 5;  // 32 x 8
#pragma unroll
        for (int i = 0; i < 32; i += 8)
            tile[ty + i][tx] = W[(size_t)(kb + ty + i) * N + nb + tx];
        __syncthreads();
#pragma unroll
        for (int i = 0; i < 32; i += 8)
            Wt[(size_t)(nb + ty + i) * K + kb + tx] = f2bf(tile[tx][ty + i]);
    } else {
        int row = bid - 6912;
        ln_row(x + (size_t)row * DM, g1, b1, y + (size_t)row * DM, threadIdx.x);
    }
}

// ---------------- LayerNorm: f32 [4096][768] -> bf16 ----------------
__global__ __launch_bounds__(256) void ln_kernel(const float* __restrict__ x,
                                                 const float* __restrict__ g,
                                                 const float* __restrict__ b,
                                                 u16* __restrict__ y) {
    int row = blockIdx.x;
    ln_row(x + (size_t)row * DM, g, b, y + (size_t)row * DM, threadIdx.x);
}

// ---------------- GEMM: A[M][K] bf16 x Bt[N][K] bf16, TMxTN tile (r17 exact) ----------------
// TN=128: 4 waves side-by-side (MF=4, NF=2)
// TN=64:  2x2 wave quadrants of 32x32 (MF=2, NF=2)
template<int TM, int TN>
__global__ __launch_bounds__(256) void gemm_bf16(
    const u16* __restrict__ A, const u16* __restrict__ Bt,
    const float* __restrict__ bias, const float* __restrict__ resid,
    float* __restrict__ outF, u16* __restrict__ outB,
    int M, int N, int K, int gelu) {
    constexpr int AP = TM / 32;              // A staging rounds
    constexpr int BP = TN / 32;              // B staging rounds
    constexpr int MF = (TN == 128) ? 4 : 2;  // M frags per wave
    constexpr int NF = 2;                    // N frags per wave
    __shared__ __align__(16) u16 As[2][TM * 64];
    __shared__ __align__(16) u16 Bs[2][TN * 64];
    int tid = threadIdx.x;
    int lane = tid & 63, wid = tid >> 6;
    int lr = lane & 15, hi = lane >> 4;
    int wrow = (TN == 128) ? 0 : (wid >> 1) * 32;
    int wcol = (TN == 128) ? wid * 32 : (wid & 1) * 32;
    int m0 = blockIdx.y * TM, n0 = blockIdx.x * TN;

    f32x4 acc[MF][NF] = {};
    int srow = tid >> 3;          // 0..31
    int sk = (tid & 7) << 3;      // 0..56
    const u16* Ag = A + (size_t)(m0 + srow) * K + sk;
    const u16* Bg = Bt + (size_t)(n0 + srow) * K + sk;

    u16x8 ar[AP], br[BP];
    auto LOAD = [&](int kt) {
#pragma unroll
        for (int p = 0; p < AP; ++p)
            ar[p] = *reinterpret_cast<const u16x8*>(Ag + (size_t)p * 32 * K + kt);
#pragma unroll
        for (int p = 0; p < BP; ++p)
            br[p] = *reinterpret_cast<const u16x8*>(Bg + (size_t)p * 32 * K + kt);
    };
    auto WRITE = [&](int buf) {
#pragma unroll
        for (int p = 0; p < AP; ++p)
            *reinterpret_cast<u16x8*>(&As[buf][swz64(srow + p * 32, sk)]) = ar[p];
#pragma unroll
        for (int p = 0; p < BP; ++p)
            *reinterpret_cast<u16x8*>(&Bs[buf][swz64(srow + p * 32, sk)]) = br[p];
    };

    int NT = K >> 6;
    LOAD(0);
    WRITE(0);
#pragma unroll 2
    for (int t = 0; t < NT; ++t) {
        if (t + 1 < NT) LOAD((t + 1) << 6);
        __syncthreads();
        const u16* as = &As[t & 1][0];
        const u16* bs = &Bs[t & 1][0];
#pragma unroll
        for (int ks = 0; ks < 2; ++ks) {
            bf16x8 af[MF], bfr[NF];
#pragma unroll
            for (int m = 0; m < MF; ++m)
                af[m] = *reinterpret_cast<const bf16x8*>(&as[swz64(wrow + m * 16 + lr, ks * 32 + hi * 8)]);
#pragma unroll
            for (int n = 0; n < NF; ++n)
                bfr[n] = *reinterpret_cast<const bf16x8*>(&bs[swz64(wcol + n * 16 + lr, ks * 32 + hi * 8)]);
            __builtin_amdgcn_s_setprio(1);
#pragma unroll
            for (int m = 0; m < MF; ++m)
#pragma unroll
                for (int n = 0; n < NF; ++n)
                    acc[m][n] = __builtin_amdgcn_mfma_f32_16x16x32_bf16(af[m], bfr[n], acc[m][n], 0, 0, 0);
            __builtin_amdgcn_s_setprio(0);
        }
        if (t + 1 < NT) WRITE((t + 1) & 1);
    }
#pragma unroll
    for (int m = 0; m < MF; ++m) {
#pragma unroll
        for (int n = 0; n < NF; ++n) {
            int col = n0 + wcol + n * 16 + lr;
            float bv = bias[col];
#pragma unroll
            for (int r = 0; r < 4; ++r) {
                int row = m0 + wrow + m * 16 + hi * 4 + r;
                float v = acc[m][n][r] + bv;
                if (gelu) v = gelu_exact(v);
                if (resid) v += resid[(size_t)row * N + col];
                if (outF) outF[(size_t)row * N + col] = v;
                if (outB) outB[(size_t)row * N + col] = f2bf(v);
            }
        }
    }
}

// ---------------- flash attention (r15 best: QBLK=64, KVBLK=128 dbuf, 256 thr) ----------------
__global__ __launch_bounds__(256, 2) void attn_kernel(const u16* __restrict__ qkv,
                                                      u16* __restrict__ attn) {
    __shared__ __align__(16) u16 Ks[2][128 * 64];   // [kv][hd], swz64
    __shared__ __align__(16) u16 Vt[2][64 * 128];   // [hd][kv], swz128
    int tid = threadIdx.x;
    int lane = tid & 63, w = tid >> 6;
    int lr = lane & 15, hi = lane >> 4;
    int upper = hi >> 1;
    const float SCL = 0.125f * 1.44269504088896340736f;  // 1/sqrt(64) * log2(e)

    int bid = blockIdx.x;
    int h = bid % NH;
    int qb = (SEQ / 64 - 1) - bid / NH;   // LPT: biggest work first

    int qrow = qb * 64 + w * 16 + lr;
    bf16x8 qf[2];
#pragma unroll
    for (int ks = 0; ks < 2; ++ks)
        qf[ks] = *reinterpret_cast<const bf16x8*>(&qkv[(size_t)qrow * 2304 + h * 192 + ks * 32 + hi * 8]);

    f32x4 acc[4] = {};
    float m_run = -INFINITY, l_run = 0.0f;   // m_run in log2 domain

    // staging lanes
    int skvr = tid >> 3;            // K: row 0..31 (+p*32)
    int skc = (tid & 7) << 3;       // K: col
    int svd = tid & 63;             // V: head-dim
    int svk = (tid >> 6) * 32;      // V: kv base
    u16x8 kr[4], vr[4];

    auto LOADKV = [&](int kb) {
#pragma unroll
        for (int p = 0; p < 4; ++p)
            kr[p] = *reinterpret_cast<const u16x8*>(
                &qkv[(size_t)(kb * 128 + skvr + p * 32) * 2304 + h * 192 + 64 + skc]);
        const u16* vb = &qkv[(size_t)(kb * 128 + svk) * 2304 + h * 192 + 128 + svd];
#pragma unroll
        for (int g = 0; g < 4; ++g)
#pragma unroll
            for (int j = 0; j < 8; ++j)
                vr[g][j] = vb[(size_t)(g * 8 + j) * 2304];
    };
    auto WRITEKV = [&](int buf) {
#pragma unroll
        for (int p = 0; p < 4; ++p)
            *reinterpret_cast<u16x8*>(&Ks[buf][swz64(skvr + p * 32, skc)]) = kr[p];
#pragma unroll
        for (int g = 0; g < 4; ++g)
            *reinterpret_cast<u16x8*>(&Vt[buf][swz128(svd, svk + g * 8)]) = vr[g];
    };

    int nt = (qb * 64 + 64 + 127) >> 7;   // causal tile count (KVBLK=128)
    LOADKV(0);
    WRITEKV(0);
    for (int kb = 0; kb < nt; ++kb) {
        if (kb + 1 < nt) LOADKV(kb + 1);
        __syncthreads();
        const u16* ksb = &Ks[kb & 1][0];
        const u16* vtb = &Vt[kb & 1][0];

        // ---- S^T = K x Q^T ----
        f32x4 s[8] = {};
        __builtin_amdgcn_s_setprio(1);
#pragma unroll
        for (int ks = 0; ks < 2; ++ks) {
#pragma unroll
            for (int n = 0; n < 8; ++n) {
                bf16x8 kf = *reinterpret_cast<const bf16x8*>(&ksb[swz64(n * 16 + lr, ks * 32 + hi * 8)]);
                s[n] = __builtin_amdgcn_mfma_f32_16x16x32_bf16(kf, qf[ks], s[n], 0, 0, 0);
            }
        }
        __builtin_amdgcn_s_setprio(0);
        // ---- causal mask: only the diagonal tile needs it ----
        float sv[8][4];
#pragma unroll
        for (int n = 0; n < 8; ++n) {
            sv[n][0] = s[n][0]; sv[n][1] = s[n][1]; sv[n][2] = s[n][2]; sv[n][3] = s[n][3];
        }
        if (kb == nt - 1) {
#pragma unroll
            for (int n = 0; n < 8; ++n)
#pragma unroll
                for (int r = 0; r < 4; ++r) {
                    int kv = kb * 128 + n * 16 + hi * 4 + r;
                    if (kv > qrow) sv[n][r] = -3.0e38f;
                }
        }
        // ---- online softmax, log2 domain, defer-max (THR=8) ----
        float t8[8];
#pragma unroll
        for (int n = 0; n < 8; ++n)
            t8[n] = fmaxf(fmaxf(sv[n][0], sv[n][1]), fmaxf(sv[n][2], sv[n][3]));
        float mx = fmaxf(fmaxf(fmaxf(t8[0], t8[1]), fmaxf(t8[2], t8[3])),
                         fmaxf(fmaxf(t8[4], t8[5]), fmaxf(t8[6], t8[7])));
        mx = fmaxf(mx, __shfl_xor(mx, 16));
        mx = fmaxf(mx, __shfl_xor(mx, 32));
        float mxs = mx * SCL;
        if (!__all(mxs <= m_run + 8.0f)) {
            float mnew = fmaxf(m_run, mxs);
            float alpha = __builtin_amdgcn_exp2f(m_run - mnew);
            l_run *= alpha;
#pragma unroll
            for (int n2 = 0; n2 < 4; ++n2)
#pragma unroll
                for (int r = 0; r < 4; ++r) acc[n2][r] *= alpha;
            m_run = mnew;
        }
        float rs = 0.0f;
#pragma unroll
        for (int n = 0; n < 8; ++n) {
            float p0 = __builtin_amdgcn_exp2f(__builtin_fmaf(sv[n][0], SCL, -m_run));
            float p1 = __builtin_amdgcn_exp2f(__builtin_fmaf(sv[n][1], SCL, -m_run));
            float p2 = __builtin_amdgcn_exp2f(__builtin_fmaf(sv[n][2], SCL, -m_run));
            float p3 = __builtin_amdgcn_exp2f(__builtin_fmaf(sv[n][3], SCL, -m_run));
            sv[n][0] = p0; sv[n][1] = p1; sv[n][2] = p2; sv[n][3] = p3;
            rs += (p0 + p1) + (p2 + p3);
        }
        rs += __shfl_xor(rs, 16);
        rs += __shfl_xor(rs, 32);
        l_run += rs;

        // ---- pack P^T to bf16 pairs in-register ----
        unsigned pk0[8], pk1[8];
#pragma unroll
        for (int n = 0; n < 8; ++n) {
            pk0[n] = pack_bf16(sv[n][0], sv[n][1]);
            pk1[n] = pack_bf16(sv[n][2], sv[n][3]);
        }
        // ---- build B-fragments of P^T via cross-lane exchange, then PV ----
        int src0 = lr + ((hi & 1) << 5);
        int src1 = src0 + 16;
#pragma unroll
        for (int ks = 0; ks < 4; ++ks) {
            union { unsigned w4[4]; bf16x8 v; } pf;
            {
                unsigned a0 = __shfl(pk0[2 * ks], src0), b0 = __shfl(pk0[2 * ks + 1], src0);
                unsigned a1 = __shfl(pk1[2 * ks], src0), b1 = __shfl(pk1[2 * ks + 1], src0);
                unsigned a2 = __shfl(pk0[2 * ks], src1), b2 = __shfl(pk0[2 * ks + 1], src1);
                unsigned a3 = __shfl(pk1[2 * ks], src1), b3 = __shfl(pk1[2 * ks + 1], src1);
                pf.w4[0] = upper ? b0 : a0;
                pf.w4[1] = upper ? b1 : a1;
                pf.w4[2] = upper ? b2 : a2;
                pf.w4[3] = upper ? b3 : a3;
            }
            __builtin_amdgcn_s_setprio(1);
#pragma unroll
            for (int n2 = 0; n2 < 4; ++n2) {
                bf16x8 vf = *reinterpret_cast<const bf16x8*>(&vtb[swz128(n2 * 16 + lr, ks * 32 + hi * 8)]);
                acc[n2] = __builtin_amdgcn_mfma_f32_16x16x32_bf16(vf, pf.v, acc[n2], 0, 0, 0);
            }
            __builtin_amdgcn_s_setprio(0);
        }
        if (kb + 1 < nt) WRITEKV((kb + 1) & 1);
    }
    // ---- store O^T -> attn[q][h*64+d], normalized ----
    float inv = 1.0f / l_run;
#pragma unroll
    for (int n2 = 0; n2 < 4; ++n2) {
#pragma unroll
        for (int r = 0; r < 4; ++r) {
            int dcol = h * 64 + n2 * 16 + hi * 4 + r;
            attn[(size_t)qrow * DM + dcol] = f2bf(acc[n2][r] * inv);
        }
    }
}

extern "C" void kernel_launch(void* const* d_in, const int* in_sizes, int n_in,
                              void* d_out, int out_size, void* d_ws, size_t ws_size,
                              hipStream_t stream) {
    const float* x      = (const float*)d_in[0];
    const float* gamma1 = (const float*)d_in[1];
    const float* beta1  = (const float*)d_in[2];
    const float* Wqkv   = (const float*)d_in[3];
    const float* bqkv   = (const float*)d_in[4];
    const float* Wo     = (const float*)d_in[5];
    const float* bo     = (const float*)d_in[6];
    const float* gamma2 = (const float*)d_in[7];
    const float* beta2  = (const float*)d_in[8];
    const float* W1     = (const float*)d_in[9];
    const float* b1     = (const float*)d_in[10];
    const float* W2     = (const float*)d_in[11];
    const float* b2     = (const float*)d_in[12];

    char* ws = (char*)d_ws;
    size_t off = 0;
    u16* WqkvT = (u16*)(ws + off); off += (size_t)2304 * 768 * 2;
    u16* WoT   = (u16*)(ws + off); off += (size_t)768 * 768 * 2;
    u16* W1T   = (u16*)(ws + off); off += (size_t)3072 * 768 * 2;
    u16* W2T   = (u16*)(ws + off); off += (size_t)768 * 3072 * 2;
    u16* B1    = (u16*)(ws + off); off += (size_t)SEQ * DM * 2;      // y1 / attn / y2
    u16* Q     = (u16*)(ws + off); off += (size_t)SEQ * HID * 2;     // qkv, then h
    float* x1  = (float*)(ws + off); off += (size_t)SEQ * DM * 4;

    // fused: 4 weight transposes + LN1 in one launch (6912 transpose blocks + 4096 LN rows)
    prep_kernel<<<dim3(11008), 256, 0, stream>>>(x, gamma1, beta1, Wqkv, Wo, W1, W2,
                                                 WqkvT, WoT, W1T, W2T, B1);
    gemm_bf16<64, 128><<<dim3(2304 / 128, SEQ / 64), 256, 0, stream>>>(B1, WqkvT, bqkv, nullptr, nullptr, Q, SEQ, 2304, 768, 0);
    attn_kernel<<<dim3((SEQ / 64) * NH), 256, 0, stream>>>(Q, B1);
    gemm_bf16<64, 64><<<dim3(768 / 64, SEQ / 64), 256, 0, stream>>>(B1, WoT, bo, x, x1, nullptr, SEQ, 768, 768, 0);
    ln_kernel<<<SEQ, 256, 0, stream>>>(x1, gamma2, beta2, B1);
    gemm_bf16<64, 128><<<dim3(3072 / 128, SEQ / 64), 256, 0, stream>>>(B1, W1T, b1, nullptr, nullptr, Q, SEQ, 3072, 768, 1);
    gemm_bf16<64, 64><<<dim3(768 / 64, SEQ / 64), 256, 0, stream>>>(Q, W2T, b2, x1, (float*)d_out, nullptr, SEQ, 768, 3072, 0);
}

// Round 20
// 207.395 us; speedup vs baseline: 1.1129x; 1.0413x over previous
//
#include <hip/hip_runtime.h>
#include <hip/hip_bf16.h>
#include <cmath>

using u16 = unsigned short;
typedef __bf16 bf16x8 __attribute__((ext_vector_type(8)));
typedef __bf16 bf16x2 __attribute__((ext_vector_type(2)));
typedef unsigned short u16x8 __attribute__((ext_vector_type(8)));
typedef float f32x4 __attribute__((ext_vector_type(4)));

#define SEQ 4096
#define DM 768
#define NH 12
#define HD 64
#define HID 3072

__device__ __forceinline__ u16 f2bf(float f) {
    union { float f; unsigned u; } v; v.f = f;
    unsigned r = v.u + 0x7fffu + ((v.u >> 16) & 1u);
    return (u16)(r >> 16);
}

__device__ __forceinline__ unsigned pack_bf16(float a, float b) {
    union { bf16x2 v; unsigned u; } c;
    c.v[0] = (__bf16)a; c.v[1] = (__bf16)b;
    return c.u;
}

// exact-gelu via A&S 7.1.26 erf poly (|eps|<=1.5e-7)
__device__ __forceinline__ float gelu_exact(float v) {
    float z = fabsf(v) * 0.70710678118654752f;
    float t = __builtin_amdgcn_rcpf(__builtin_fmaf(0.3275911f, z, 1.0f));
    float p = t * __builtin_fmaf(t, __builtin_fmaf(t, __builtin_fmaf(t,
                __builtin_fmaf(t, 1.061405429f, -1.453152027f),
                1.421413741f), -0.284496736f), 0.254829592f);
    float e = __builtin_amdgcn_exp2f(-z * z * 1.44269504088896341f);
    float erfv = __builtin_fmaf(-p, e, 1.0f);
    erfv = (v < 0.0f) ? -erfv : erfv;
    return 0.5f * v * (1.0f + erfv);
}

// XOR swizzle, 64-u16 rows (8 chunks of 16B): chunk ^= row&7
__device__ __forceinline__ int swz64(int row, int k) {
    return (row << 6) | ((((k >> 3) ^ row) & 7) << 3) | (k & 7);
}
// XOR swizzle, 128-u16 rows (16 chunks of 16B): chunk ^= row&15
__device__ __forceinline__ int swz128(int row, int k) {
    return (row << 7) | ((((k >> 3) ^ row) & 15) << 3) | (k & 7);
}

__device__ __forceinline__ void ln_row(const float* __restrict__ xr,
                                       const float* __restrict__ g,
                                       const float* __restrict__ b,
                                       u16* __restrict__ yr, int t) {
    float v0 = xr[t], v1 = xr[t + 256], v2 = xr[t + 512];
    float s = v0 + v1 + v2;
#pragma unroll
    for (int m = 32; m; m >>= 1) s += __shfl_xor(s, m);
    __shared__ float red[4], red2[4];
    int wid = t >> 6, lane = t & 63;
    if (lane == 0) red[wid] = s;
    __syncthreads();
    float mean = (red[0] + red[1] + red[2] + red[3]) * (1.0f / DM);
    float d0 = v0 - mean, d1 = v1 - mean, d2 = v2 - mean;
    float q = d0 * d0 + d1 * d1 + d2 * d2;
#pragma unroll
    for (int m = 32; m; m >>= 1) q += __shfl_xor(q, m);
    if (lane == 0) red2[wid] = q;
    __syncthreads();
    float var = (red2[0] + red2[1] + red2[2] + red2[3]) * (1.0f / DM);
    float rstd = rsqrtf(var + 1e-5f);
    yr[t]       = f2bf(d0 * rstd * g[t]       + b[t]);
    yr[t + 256] = f2bf(d1 * rstd * g[t + 256] + b[t + 256]);
    yr[t + 512] = f2bf(d2 * rstd * g[t + 512] + b[t + 512]);
}

// ---------------- fused prep: 4 weight transposes + LN1, one launch ----------------
__global__ __launch_bounds__(256) void prep_kernel(
    const float* __restrict__ x, const float* __restrict__ g1, const float* __restrict__ b1,
    const float* __restrict__ Wqkv, const float* __restrict__ Wo,
    const float* __restrict__ W1, const float* __restrict__ W2,
    u16* __restrict__ WqkvT, u16* __restrict__ WoT,
    u16* __restrict__ W1T, u16* __restrict__ W2T, u16* __restrict__ y) {
    int bid = blockIdx.x;
    if (bid < 6912) {
        const float* W; u16* Wt; int K, N, ntx, b;
        if (bid < 1728)      { W = Wqkv; Wt = WqkvT; K = 768;  N = 2304; ntx = 72; b = bid; }
        else if (bid < 2304) { W = Wo;   Wt = WoT;   K = 768;  N = 768;  ntx = 24; b = bid - 1728; }
        else if (bid < 4608) { W = W1;   Wt = W1T;   K = 768;  N = 3072; ntx = 96; b = bid - 2304; }
        else                 { W = W2;   Wt = W2T;   K = 3072; N = 768;  ntx = 24; b = bid - 4608; }
        int nb = (b % ntx) * 32, kb = (b / ntx) * 32;
        __shared__ float tile[32][33];
        int tx = threadIdx.x & 31, ty = threadIdx.x >> 5;  // 32 x 8
#pragma unroll
        for (int i = 0; i < 32; i += 8)
            tile[ty + i][tx] = W[(size_t)(kb + ty + i) * N + nb + tx];
        __syncthreads();
#pragma unroll
        for (int i = 0; i < 32; i += 8)
            Wt[(size_t)(nb + ty + i) * K + kb + tx] = f2bf(tile[tx][ty + i]);
    } else {
        int row = bid - 6912;
        ln_row(x + (size_t)row * DM, g1, b1, y + (size_t)row * DM, threadIdx.x);
    }
}

// ---------------- V pre-transpose: qkv [4096][2304] -> VtG [NH][64][SEQ] ----------------
__global__ __launch_bounds__(256) void vtrans_kernel(const u16* __restrict__ qkv,
                                                     u16* __restrict__ VtG) {
    __shared__ u16 tile[64][68];   // +4 pad: transposed-col read is 2-4 way (free-ish)
    int kvb = blockIdx.x;          // 64 kv rows per block
    int h = blockIdx.y;
    int t = threadIdx.x;
    int r0 = t >> 3, c0 = (t & 7) << 3;
#pragma unroll
    for (int p = 0; p < 2; ++p) {
        u16x8 v = *reinterpret_cast<const u16x8*>(
            &qkv[(size_t)(kvb * 64 + r0 + p * 32) * 2304 + h * 192 + 128 + c0]);
#pragma unroll
        for (int j = 0; j < 8; ++j)
            tile[r0 + p * 32][c0 + j] = v[j];
    }
    __syncthreads();
    int kv = t & 63, db = (t >> 6) << 4;
#pragma unroll
    for (int i = 0; i < 16; ++i) {
        int d = db + i;
        VtG[(size_t)(h * 64 + d) * SEQ + kvb * 64 + kv] = tile[kv][d];
    }
}

// ---------------- LayerNorm ----------------
__global__ __launch_bounds__(256) void ln_kernel(const float* __restrict__ x,
                                                 const float* __restrict__ g,
                                                 const float* __restrict__ b,
                                                 u16* __restrict__ y) {
    int row = blockIdx.x;
    ln_row(x + (size_t)row * DM, g, b, y + (size_t)row * DM, threadIdx.x);
}

// ---------------- GEMM: A[M][K] bf16 x Bt[N][K] bf16, TMxTN tile (r17 exact) ----------------
template<int TM, int TN>
__global__ __launch_bounds__(256) void gemm_bf16(
    const u16* __restrict__ A, const u16* __restrict__ Bt,
    const float* __restrict__ bias, const float* __restrict__ resid,
    float* __restrict__ outF, u16* __restrict__ outB,
    int M, int N, int K, int gelu) {
    constexpr int AP = TM / 32;
    constexpr int BP = TN / 32;
    constexpr int MF = (TN == 128) ? 4 : 2;
    constexpr int NF = 2;
    __shared__ __align__(16) u16 As[2][TM * 64];
    __shared__ __align__(16) u16 Bs[2][TN * 64];
    int tid = threadIdx.x;
    int lane = tid & 63, wid = tid >> 6;
    int lr = lane & 15, hi = lane >> 4;
    int wrow = (TN == 128) ? 0 : (wid >> 1) * 32;
    int wcol = (TN == 128) ? wid * 32 : (wid & 1) * 32;
    int m0 = blockIdx.y * TM, n0 = blockIdx.x * TN;

    f32x4 acc[MF][NF] = {};
    int srow = tid >> 3;
    int sk = (tid & 7) << 3;
    const u16* Ag = A + (size_t)(m0 + srow) * K + sk;
    const u16* Bg = Bt + (size_t)(n0 + srow) * K + sk;

    u16x8 ar[AP], br[BP];
    auto LOAD = [&](int kt) {
#pragma unroll
        for (int p = 0; p < AP; ++p)
            ar[p] = *reinterpret_cast<const u16x8*>(Ag + (size_t)p * 32 * K + kt);
#pragma unroll
        for (int p = 0; p < BP; ++p)
            br[p] = *reinterpret_cast<const u16x8*>(Bg + (size_t)p * 32 * K + kt);
    };
    auto WRITE = [&](int buf) {
#pragma unroll
        for (int p = 0; p < AP; ++p)
            *reinterpret_cast<u16x8*>(&As[buf][swz64(srow + p * 32, sk)]) = ar[p];
#pragma unroll
        for (int p = 0; p < BP; ++p)
            *reinterpret_cast<u16x8*>(&Bs[buf][swz64(srow + p * 32, sk)]) = br[p];
    };

    int NT = K >> 6;
    LOAD(0);
    WRITE(0);
#pragma unroll 2
    for (int t = 0; t < NT; ++t) {
        if (t + 1 < NT) LOAD((t + 1) << 6);
        __syncthreads();
        const u16* as = &As[t & 1][0];
        const u16* bs = &Bs[t & 1][0];
#pragma unroll
        for (int ks = 0; ks < 2; ++ks) {
            bf16x8 af[MF], bfr[NF];
#pragma unroll
            for (int m = 0; m < MF; ++m)
                af[m] = *reinterpret_cast<const bf16x8*>(&as[swz64(wrow + m * 16 + lr, ks * 32 + hi * 8)]);
#pragma unroll
            for (int n = 0; n < NF; ++n)
                bfr[n] = *reinterpret_cast<const bf16x8*>(&bs[swz64(wcol + n * 16 + lr, ks * 32 + hi * 8)]);
            __builtin_amdgcn_s_setprio(1);
#pragma unroll
            for (int m = 0; m < MF; ++m)
#pragma unroll
                for (int n = 0; n < NF; ++n)
                    acc[m][n] = __builtin_amdgcn_mfma_f32_16x16x32_bf16(af[m], bfr[n], acc[m][n], 0, 0, 0);
            __builtin_amdgcn_s_setprio(0);
        }
        if (t + 1 < NT) WRITE((t + 1) & 1);
    }
#pragma unroll
    for (int m = 0; m < MF; ++m) {
#pragma unroll
        for (int n = 0; n < NF; ++n) {
            int col = n0 + wcol + n * 16 + lr;
            float bv = bias[col];
#pragma unroll
            for (int r = 0; r < 4; ++r) {
                int row = m0 + wrow + m * 16 + hi * 4 + r;
                float v = acc[m][n][r] + bv;
                if (gelu) v = gelu_exact(v);
                if (resid) v += resid[(size_t)row * N + col];
                if (outF) outF[(size_t)row * N + col] = v;
                if (outB) outB[(size_t)row * N + col] = f2bf(v);
            }
        }
    }
}

// ---------------- flash attention (r15 schedule + pre-transposed V) ----------------
__global__ __launch_bounds__(256, 2) void attn_kernel(const u16* __restrict__ qkv,
                                                      const u16* __restrict__ VtG,
                                                      u16* __restrict__ attn) {
    __shared__ __align__(16) u16 Ks[2][128 * 64];   // [kv][hd], swz64
    __shared__ __align__(16) u16 Vt[2][64 * 128];   // [hd][kv], swz128
    int tid = threadIdx.x;
    int lane = tid & 63, w = tid >> 6;
    int lr = lane & 15, hi = lane >> 4;
    int upper = hi >> 1;
    const float SCL = 0.125f * 1.44269504088896340736f;  // 1/sqrt(64) * log2(e)

    int bid = blockIdx.x;
    int h = bid % NH;
    int qb = (SEQ / 64 - 1) - bid / NH;   // LPT: biggest work first

    int qrow = qb * 64 + w * 16 + lr;
    bf16x8 qf[2];
#pragma unroll
    for (int ks = 0; ks < 2; ++ks)
        qf[ks] = *reinterpret_cast<const bf16x8*>(&qkv[(size_t)qrow * 2304 + h * 192 + ks * 32 + hi * 8]);

    f32x4 acc[4] = {};
    float m_run = -INFINITY, l_run = 0.0f;   // m_run in log2 domain

    // staging lanes
    int skvr = tid >> 3;            // K: row 0..31 (+p*32)
    int skc = (tid & 7) << 3;       // K: col
    int svd = tid >> 4;             // V: d row 0..15 (+p*16)
    int svk = (tid & 15) << 3;      // V: kv col (16 lanes cover 128 kv)
    u16x8 kr[4], vr[4];

    auto LOADKV = [&](int kb) {
#pragma unroll
        for (int p = 0; p < 4; ++p)
            kr[p] = *reinterpret_cast<const u16x8*>(
                &qkv[(size_t)(kb * 128 + skvr + p * 32) * 2304 + h * 192 + 64 + skc]);
#pragma unroll
        for (int p = 0; p < 4; ++p)
            vr[p] = *reinterpret_cast<const u16x8*>(
                &VtG[(size_t)(h * 64 + svd + p * 16) * SEQ + kb * 128 + svk]);
    };
    auto WRITEKV = [&](int buf) {
#pragma unroll
        for (int p = 0; p < 4; ++p)
            *reinterpret_cast<u16x8*>(&Ks[buf][swz64(skvr + p * 32, skc)]) = kr[p];
#pragma unroll
        for (int p = 0; p < 4; ++p)
            *reinterpret_cast<u16x8*>(&Vt[buf][swz128(svd + p * 16, svk)]) = vr[p];
    };

    int nt = (qb * 64 + 64 + 127) >> 7;   // causal tile count (KVBLK=128)
    LOADKV(0);
    WRITEKV(0);
    for (int kb = 0; kb < nt; ++kb) {
        if (kb + 1 < nt) LOADKV(kb + 1);
        __syncthreads();
        const u16* ksb = &Ks[kb & 1][0];
        const u16* vtb = &Vt[kb & 1][0];

        // ---- S^T = K x Q^T ----
        f32x4 s[8] = {};
        __builtin_amdgcn_s_setprio(1);
#pragma unroll
        for (int ks = 0; ks < 2; ++ks) {
#pragma unroll
            for (int n = 0; n < 8; ++n) {
                bf16x8 kf = *reinterpret_cast<const bf16x8*>(&ksb[swz64(n * 16 + lr, ks * 32 + hi * 8)]);
                s[n] = __builtin_amdgcn_mfma_f32_16x16x32_bf16(kf, qf[ks], s[n], 0, 0, 0);
            }
        }
        __builtin_amdgcn_s_setprio(0);
        // ---- causal mask: only the diagonal tile needs it ----
        float sv[8][4];
#pragma unroll
        for (int n = 0; n < 8; ++n) {
            sv[n][0] = s[n][0]; sv[n][1] = s[n][1]; sv[n][2] = s[n][2]; sv[n][3] = s[n][3];
        }
        if (kb == nt - 1) {
#pragma unroll
            for (int n = 0; n < 8; ++n)
#pragma unroll
                for (int r = 0; r < 4; ++r) {
                    int kv = kb * 128 + n * 16 + hi * 4 + r;
                    if (kv > qrow) sv[n][r] = -3.0e38f;
                }
        }
        // ---- online softmax, log2 domain, defer-max (THR=8) ----
        float t8[8];
#pragma unroll
        for (int n = 0; n < 8; ++n)
            t8[n] = fmaxf(fmaxf(sv[n][0], sv[n][1]), fmaxf(sv[n][2], sv[n][3]));
        float mx = fmaxf(fmaxf(fmaxf(t8[0], t8[1]), fmaxf(t8[2], t8[3])),
                         fmaxf(fmaxf(t8[4], t8[5]), fmaxf(t8[6], t8[7])));
        mx = fmaxf(mx, __shfl_xor(mx, 16));
        mx = fmaxf(mx, __shfl_xor(mx, 32));
        float mxs = mx * SCL;
        if (!__all(mxs <= m_run + 8.0f)) {
            float mnew = fmaxf(m_run, mxs);
            float alpha = __builtin_amdgcn_exp2f(m_run - mnew);
            l_run *= alpha;
#pragma unroll
            for (int n2 = 0; n2 < 4; ++n2)
#pragma unroll
                for (int r = 0; r < 4; ++r) acc[n2][r] *= alpha;
            m_run = mnew;
        }
        float rs = 0.0f;
#pragma unroll
        for (int n = 0; n < 8; ++n) {
            float p0 = __builtin_amdgcn_exp2f(__builtin_fmaf(sv[n][0], SCL, -m_run));
            float p1 = __builtin_amdgcn_exp2f(__builtin_fmaf(sv[n][1], SCL, -m_run));
            float p2 = __builtin_amdgcn_exp2f(__builtin_fmaf(sv[n][2], SCL, -m_run));
            float p3 = __builtin_amdgcn_exp2f(__builtin_fmaf(sv[n][3], SCL, -m_run));
            sv[n][0] = p0; sv[n][1] = p1; sv[n][2] = p2; sv[n][3] = p3;
            rs += (p0 + p1) + (p2 + p3);
        }
        rs += __shfl_xor(rs, 16);
        rs += __shfl_xor(rs, 32);
        l_run += rs;

        // ---- pack P^T to bf16 pairs in-register ----
        unsigned pk0[8], pk1[8];
#pragma unroll
        for (int n = 0; n < 8; ++n) {
            pk0[n] = pack_bf16(sv[n][0], sv[n][1]);
            pk1[n] = pack_bf16(sv[n][2], sv[n][3]);
        }
        // ---- build B-fragments of P^T via cross-lane exchange, then PV ----
        int src0 = lr + ((hi & 1) << 5);
        int src1 = src0 + 16;
#pragma unroll
        for (int ks = 0; ks < 4; ++ks) {
            union { unsigned w4[4]; bf16x8 v; } pf;
            {
                unsigned a0 = __shfl(pk0[2 * ks], src0), b0 = __shfl(pk0[2 * ks + 1], src0);
                unsigned a1 = __shfl(pk1[2 * ks], src0), b1 = __shfl(pk1[2 * ks + 1], src0);
                unsigned a2 = __shfl(pk0[2 * ks], src1), b2 = __shfl(pk0[2 * ks + 1], src1);
                unsigned a3 = __shfl(pk1[2 * ks], src1), b3 = __shfl(pk1[2 * ks + 1], src1);
                pf.w4[0] = upper ? b0 : a0;
                pf.w4[1] = upper ? b1 : a1;
                pf.w4[2] = upper ? b2 : a2;
                pf.w4[3] = upper ? b3 : a3;
            }
            __builtin_amdgcn_s_setprio(1);
#pragma unroll
            for (int n2 = 0; n2 < 4; ++n2) {
                bf16x8 vf = *reinterpret_cast<const bf16x8*>(&vtb[swz128(n2 * 16 + lr, ks * 32 + hi * 8)]);
                acc[n2] = __builtin_amdgcn_mfma_f32_16x16x32_bf16(vf, pf.v, acc[n2], 0, 0, 0);
            }
            __builtin_amdgcn_s_setprio(0);
        }
        if (kb + 1 < nt) WRITEKV((kb + 1) & 1);
    }
    // ---- store O^T -> attn[q][h*64+d], normalized ----
    float inv = 1.0f / l_run;
#pragma unroll
    for (int n2 = 0; n2 < 4; ++n2) {
#pragma unroll
        for (int r = 0; r < 4; ++r) {
            int dcol = h * 64 + n2 * 16 + hi * 4 + r;
            attn[(size_t)qrow * DM + dcol] = f2bf(acc[n2][r] * inv);
        }
    }
}

extern "C" void kernel_launch(void* const* d_in, const int* in_sizes, int n_in,
                              void* d_out, int out_size, void* d_ws, size_t ws_size,
                              hipStream_t stream) {
    const float* x      = (const float*)d_in[0];
    const float* gamma1 = (const float*)d_in[1];
    const float* beta1  = (const float*)d_in[2];
    const float* Wqkv   = (const float*)d_in[3];
    const float* bqkv   = (const float*)d_in[4];
    const float* Wo     = (const float*)d_in[5];
    const float* bo     = (const float*)d_in[6];
    const float* gamma2 = (const float*)d_in[7];
    const float* beta2  = (const float*)d_in[8];
    const float* W1     = (const float*)d_in[9];
    const float* b1     = (const float*)d_in[10];
    const float* W2     = (const float*)d_in[11];
    const float* b2     = (const float*)d_in[12];

    char* ws = (char*)d_ws;
    size_t off = 0;
    u16* WqkvT = (u16*)(ws + off); off += (size_t)2304 * 768 * 2;
    u16* WoT   = (u16*)(ws + off); off += (size_t)768 * 768 * 2;
    u16* W1T   = (u16*)(ws + off); off += (size_t)3072 * 768 * 2;
    u16* W2T   = (u16*)(ws + off); off += (size_t)768 * 3072 * 2;
    u16* B1    = (u16*)(ws + off); off += (size_t)SEQ * DM * 2;      // y1 / attn / y2
    u16* Q     = (u16*)(ws + off); off += (size_t)SEQ * HID * 2;     // qkv, then h
    float* x1  = (float*)(ws + off); off += (size_t)SEQ * DM * 4;

    // VtG [NH][64][SEQ] lives in x1's region (x1 is dead until the Wo GEMM writes it;
    // attn consumes VtG before that). 6.29 MB <= x1's 12.58 MB.
    u16* VtG = (u16*)x1;

    prep_kernel<<<dim3(11008), 256, 0, stream>>>(x, gamma1, beta1, Wqkv, Wo, W1, W2,
                                                 WqkvT, WoT, W1T, W2T, B1);
    gemm_bf16<64, 128><<<dim3(2304 / 128, SEQ / 64), 256, 0, stream>>>(B1, WqkvT, bqkv, nullptr, nullptr, Q, SEQ, 2304, 768, 0);
    vtrans_kernel<<<dim3(SEQ / 64, NH), 256, 0, stream>>>(Q, VtG);
    attn_kernel<<<dim3((SEQ / 64) * NH), 256, 0, stream>>>(Q, VtG, B1);
    gemm_bf16<64, 64><<<dim3(768 / 64, SEQ / 64), 256, 0, stream>>>(B1, WoT, bo, x, x1, nullptr, SEQ, 768, 768, 0);
    ln_kernel<<<SEQ, 256, 0, stream>>>(x1, gamma2, beta2, B1);
    gemm_bf16<64, 128><<<dim3(3072 / 128, SEQ / 64), 256, 0, stream>>>(B1, W1T, b1, nullptr, nullptr, Q, SEQ, 3072, 768, 1);
    gemm_bf16<64, 64><<<dim3(768 / 64, SEQ / 64), 256, 0, stream>>>(Q, W2T, b2, x1, (float*)d_out, nullptr, SEQ, 768, 3072, 0);
}

// Round 21
// 206.348 us; speedup vs baseline: 1.1186x; 1.0051x over previous
//
#include <hip/hip_runtime.h>
#include <hip/hip_bf16.h>
#include <cmath>

using u16 = unsigned short;
typedef __bf16 bf16x8 __attribute__((ext_vector_type(8)));
typedef __bf16 bf16x2 __attribute__((ext_vector_type(2)));
typedef unsigned short u16x8 __attribute__((ext_vector_type(8)));
typedef unsigned short u16x4 __attribute__((ext_vector_type(4)));
typedef float f32x4 __attribute__((ext_vector_type(4)));

#define SEQ 4096
#define DM 768
#define NH 12
#define HD 64
#define HID 3072

__device__ __forceinline__ u16 f2bf(float f) {
    union { float f; unsigned u; } v; v.f = f;
    unsigned r = v.u + 0x7fffu + ((v.u >> 16) & 1u);
    return (u16)(r >> 16);
}

__device__ __forceinline__ unsigned pack_bf16(float a, float b) {
    union { bf16x2 v; unsigned u; } c;
    c.v[0] = (__bf16)a; c.v[1] = (__bf16)b;
    return c.u;
}

// exact-gelu via A&S 7.1.26 erf poly (|eps|<=1.5e-7)
__device__ __forceinline__ float gelu_exact(float v) {
    float z = fabsf(v) * 0.70710678118654752f;
    float t = __builtin_amdgcn_rcpf(__builtin_fmaf(0.3275911f, z, 1.0f));
    float p = t * __builtin_fmaf(t, __builtin_fmaf(t, __builtin_fmaf(t,
                __builtin_fmaf(t, 1.061405429f, -1.453152027f),
                1.421413741f), -0.284496736f), 0.254829592f);
    float e = __builtin_amdgcn_exp2f(-z * z * 1.44269504088896341f);
    float erfv = __builtin_fmaf(-p, e, 1.0f);
    erfv = (v < 0.0f) ? -erfv : erfv;
    return 0.5f * v * (1.0f + erfv);
}

// XOR swizzle, 64-u16 rows (8 chunks of 16B): chunk ^= row&7
__device__ __forceinline__ int swz64(int row, int k) {
    return (row << 6) | ((((k >> 3) ^ row) & 7) << 3) | (k & 7);
}
// XOR swizzle, 128-u16 rows (16 chunks of 16B): chunk ^= row&15
__device__ __forceinline__ int swz128(int row, int k) {
    return (row << 7) | ((((k >> 3) ^ row) & 15) << 3) | (k & 7);
}

__device__ __forceinline__ void ln_row(const float* __restrict__ xr,
                                       const float* __restrict__ g,
                                       const float* __restrict__ b,
                                       u16* __restrict__ yr, int t) {
    float v0 = xr[t], v1 = xr[t + 256], v2 = xr[t + 512];
    float s = v0 + v1 + v2;
#pragma unroll
    for (int m = 32; m; m >>= 1) s += __shfl_xor(s, m);
    __shared__ float red[4], red2[4];
    int wid = t >> 6, lane = t & 63;
    if (lane == 0) red[wid] = s;
    __syncthreads();
    float mean = (red[0] + red[1] + red[2] + red[3]) * (1.0f / DM);
    float d0 = v0 - mean, d1 = v1 - mean, d2 = v2 - mean;
    float q = d0 * d0 + d1 * d1 + d2 * d2;
#pragma unroll
    for (int m = 32; m; m >>= 1) q += __shfl_xor(q, m);
    if (lane == 0) red2[wid] = q;
    __syncthreads();
    float var = (red2[0] + red2[1] + red2[2] + red2[3]) * (1.0f / DM);
    float rstd = rsqrtf(var + 1e-5f);
    yr[t]       = f2bf(d0 * rstd * g[t]       + b[t]);
    yr[t + 256] = f2bf(d1 * rstd * g[t + 256] + b[t + 256]);
    yr[t + 512] = f2bf(d2 * rstd * g[t + 512] + b[t + 512]);
}

// ---------------- fused prep: 4 weight transposes + LN1, one launch ----------------
__global__ __launch_bounds__(256) void prep_kernel(
    const float* __restrict__ x, const float* __restrict__ g1, const float* __restrict__ b1,
    const float* __restrict__ Wqkv, const float* __restrict__ Wo,
    const float* __restrict__ W1, const float* __restrict__ W2,
    u16* __restrict__ WqkvT, u16* __restrict__ WoT,
    u16* __restrict__ W1T, u16* __restrict__ W2T, u16* __restrict__ y) {
    int bid = blockIdx.x;
    if (bid < 6912) {
        const float* W; u16* Wt; int K, N, ntx, b;
        if (bid < 1728)      { W = Wqkv; Wt = WqkvT; K = 768;  N = 2304; ntx = 72; b = bid; }
        else if (bid < 2304) { W = Wo;   Wt = WoT;   K = 768;  N = 768;  ntx = 24; b = bid - 1728; }
        else if (bid < 4608) { W = W1;   Wt = W1T;   K = 768;  N = 3072; ntx = 96; b = bid - 2304; }
        else                 { W = W2;   Wt = W2T;   K = 3072; N = 768;  ntx = 24; b = bid - 4608; }
        int nb = (b % ntx) * 32, kb = (b / ntx) * 32;
        __shared__ float tile[32][33];
        int tx = threadIdx.x & 31, ty = threadIdx.x >> 5;  // 32 x 8
#pragma unroll
        for (int i = 0; i < 32; i += 8)
            tile[ty + i][tx] = W[(size_t)(kb + ty + i) * N + nb + tx];
        __syncthreads();
#pragma unroll
        for (int i = 0; i < 32; i += 8)
            Wt[(size_t)(nb + ty + i) * K + kb + tx] = f2bf(tile[tx][ty + i]);
    } else {
        int row = bid - 6912;
        ln_row(x + (size_t)row * DM, g1, b1, y + (size_t)row * DM, threadIdx.x);
    }
}

// ---------------- LayerNorm ----------------
__global__ __launch_bounds__(256) void ln_kernel(const float* __restrict__ x,
                                                 const float* __restrict__ g,
                                                 const float* __restrict__ b,
                                                 u16* __restrict__ y) {
    int row = blockIdx.x;
    ln_row(x + (size_t)row * DM, g, b, y + (size_t)row * DM, threadIdx.x);
}

// ---------------- GEMM: A[M][K] bf16 x Bt[N][K] bf16, TMxTN tile ----------------
// r17 schedule + 1D grid with XCD-chunked bijective swizzle (T1): each XCD gets
// 8 contiguous M-bands -> per-XCD working set (A-chunk 0.75MB + full B) fits
// its private 4MB L2 -> loads at L2 latency in this latency-bound regime.
// Optional vtg: QKV epilogue writes V columns transposed to VtG (fuses vtrans).
template<int TM, int TN>
__global__ __launch_bounds__(256) void gemm_bf16(
    const u16* __restrict__ A, const u16* __restrict__ Bt,
    const float* __restrict__ bias, const float* __restrict__ resid,
    float* __restrict__ outF, u16* __restrict__ outB, u16* __restrict__ vtg,
    int M, int N, int K, int gelu) {
    constexpr int AP = TM / 32;
    constexpr int BP = TN / 32;
    constexpr int MF = (TN == 128) ? 4 : 2;
    constexpr int NF = 2;
    __shared__ __align__(16) u16 As[2][TM * 64];
    __shared__ __align__(16) u16 Bs[2][TN * 64];
    int tid = threadIdx.x;
    int lane = tid & 63, wid = tid >> 6;
    int lr = lane & 15, hi = lane >> 4;
    int wrow = (TN == 128) ? 0 : (wid >> 1) * 32;
    int wcol = (TN == 128) ? wid * 32 : (wid & 1) * 32;

    // XCD-chunked bijective swizzle (grid always divisible by 8)
    int nwg = gridDim.x;
    int wg = (blockIdx.x & 7) * (nwg >> 3) + (blockIdx.x >> 3);
    int nbx = N / TN;
    int m0 = (wg / nbx) * TM, n0 = (wg % nbx) * TN;

    f32x4 acc[MF][NF] = {};
    int srow = tid >> 3;
    int sk = (tid & 7) << 3;
    const u16* Ag = A + (size_t)(m0 + srow) * K + sk;
    const u16* Bg = Bt + (size_t)(n0 + srow) * K + sk;

    u16x8 ar[AP], br[BP];
    auto LOAD = [&](int kt) {
#pragma unroll
        for (int p = 0; p < AP; ++p)
            ar[p] = *reinterpret_cast<const u16x8*>(Ag + (size_t)p * 32 * K + kt);
#pragma unroll
        for (int p = 0; p < BP; ++p)
            br[p] = *reinterpret_cast<const u16x8*>(Bg + (size_t)p * 32 * K + kt);
    };
    auto WRITE = [&](int buf) {
#pragma unroll
        for (int p = 0; p < AP; ++p)
            *reinterpret_cast<u16x8*>(&As[buf][swz64(srow + p * 32, sk)]) = ar[p];
#pragma unroll
        for (int p = 0; p < BP; ++p)
            *reinterpret_cast<u16x8*>(&Bs[buf][swz64(srow + p * 32, sk)]) = br[p];
    };

    int NT = K >> 6;
    LOAD(0);
    WRITE(0);
#pragma unroll 2
    for (int t = 0; t < NT; ++t) {
        if (t + 1 < NT) LOAD((t + 1) << 6);
        __syncthreads();
        const u16* as = &As[t & 1][0];
        const u16* bs = &Bs[t & 1][0];
#pragma unroll
        for (int ks = 0; ks < 2; ++ks) {
            bf16x8 af[MF], bfr[NF];
#pragma unroll
            for (int m = 0; m < MF; ++m)
                af[m] = *reinterpret_cast<const bf16x8*>(&as[swz64(wrow + m * 16 + lr, ks * 32 + hi * 8)]);
#pragma unroll
            for (int n = 0; n < NF; ++n)
                bfr[n] = *reinterpret_cast<const bf16x8*>(&bs[swz64(wcol + n * 16 + lr, ks * 32 + hi * 8)]);
            __builtin_amdgcn_s_setprio(1);
#pragma unroll
            for (int m = 0; m < MF; ++m)
#pragma unroll
                for (int n = 0; n < NF; ++n)
                    acc[m][n] = __builtin_amdgcn_mfma_f32_16x16x32_bf16(af[m], bfr[n], acc[m][n], 0, 0, 0);
            __builtin_amdgcn_s_setprio(0);
        }
        if (t + 1 < NT) WRITE((t + 1) & 1);
    }
#pragma unroll
    for (int m = 0; m < MF; ++m) {
#pragma unroll
        for (int n = 0; n < NF; ++n) {
            int col = n0 + wcol + n * 16 + lr;
            float bv = bias[col];
            u16 q4[4];
#pragma unroll
            for (int r = 0; r < 4; ++r) {
                int row = m0 + wrow + m * 16 + hi * 4 + r;
                float v = acc[m][n][r] + bv;
                if (gelu) v = gelu_exact(v);
                if (resid) v += resid[(size_t)row * N + col];
                q4[r] = f2bf(v);
                if (outF) outF[(size_t)row * N + col] = v;
                if (outB) outB[(size_t)row * N + col] = q4[r];
            }
            if (vtg) {
                // V columns of qkv: c = col%192 in [128,192) -> write transposed
                int h = col / 192;
                int c = col - h * 192;
                if (c >= 128) {
                    int row0 = m0 + wrow + m * 16 + hi * 4;
                    u16x4 vv; vv[0] = q4[0]; vv[1] = q4[1]; vv[2] = q4[2]; vv[3] = q4[3];
                    *reinterpret_cast<u16x4*>(&vtg[(size_t)(h * 64 + c - 128) * SEQ + row0]) = vv;
                }
            }
        }
    }
}

// ---------------- flash attention (r20: r15 schedule + pre-transposed V) ----------------
__global__ __launch_bounds__(256, 2) void attn_kernel(const u16* __restrict__ qkv,
                                                      const u16* __restrict__ VtG,
                                                      u16* __restrict__ attn) {
    __shared__ __align__(16) u16 Ks[2][128 * 64];   // [kv][hd], swz64
    __shared__ __align__(16) u16 Vt[2][64 * 128];   // [hd][kv], swz128
    int tid = threadIdx.x;
    int lane = tid & 63, w = tid >> 6;
    int lr = lane & 15, hi = lane >> 4;
    int upper = hi >> 1;
    const float SCL = 0.125f * 1.44269504088896340736f;  // 1/sqrt(64) * log2(e)

    int bid = blockIdx.x;
    int h = bid % NH;
    int qb = (SEQ / 64 - 1) - bid / NH;   // LPT: biggest work first

    int qrow = qb * 64 + w * 16 + lr;
    bf16x8 qf[2];
#pragma unroll
    for (int ks = 0; ks < 2; ++ks)
        qf[ks] = *reinterpret_cast<const bf16x8*>(&qkv[(size_t)qrow * 2304 + h * 192 + ks * 32 + hi * 8]);

    f32x4 acc[4] = {};
    float m_run = -INFINITY, l_run = 0.0f;   // m_run in log2 domain

    // staging lanes
    int skvr = tid >> 3;            // K: row 0..31 (+p*32)
    int skc = (tid & 7) << 3;       // K: col
    int svd = tid >> 4;             // V: d row 0..15 (+p*16)
    int svk = (tid & 15) << 3;      // V: kv col (16 lanes cover 128 kv)
    u16x8 kr[4], vr[4];

    auto LOADKV = [&](int kb) {
#pragma unroll
        for (int p = 0; p < 4; ++p)
            kr[p] = *reinterpret_cast<const u16x8*>(
                &qkv[(size_t)(kb * 128 + skvr + p * 32) * 2304 + h * 192 + 64 + skc]);
#pragma unroll
        for (int p = 0; p < 4; ++p)
            vr[p] = *reinterpret_cast<const u16x8*>(
                &VtG[(size_t)(h * 64 + svd + p * 16) * SEQ + kb * 128 + svk]);
    };
    auto WRITEKV = [&](int buf) {
#pragma unroll
        for (int p = 0; p < 4; ++p)
            *reinterpret_cast<u16x8*>(&Ks[buf][swz64(skvr + p * 32, skc)]) = kr[p];
#pragma unroll
        for (int p = 0; p < 4; ++p)
            *reinterpret_cast<u16x8*>(&Vt[buf][swz128(svd + p * 16, svk)]) = vr[p];
    };

    int nt = (qb * 64 + 64 + 127) >> 7;   // causal tile count (KVBLK=128)
    LOADKV(0);
    WRITEKV(0);
    for (int kb = 0; kb < nt; ++kb) {
        if (kb + 1 < nt) LOADKV(kb + 1);
        __syncthreads();
        const u16* ksb = &Ks[kb & 1][0];
        const u16* vtb = &Vt[kb & 1][0];

        // ---- S^T = K x Q^T ----
        f32x4 s[8] = {};
        __builtin_amdgcn_s_setprio(1);
#pragma unroll
        for (int ks = 0; ks < 2; ++ks) {
#pragma unroll
            for (int n = 0; n < 8; ++n) {
                bf16x8 kf = *reinterpret_cast<const bf16x8*>(&ksb[swz64(n * 16 + lr, ks * 32 + hi * 8)]);
                s[n] = __builtin_amdgcn_mfma_f32_16x16x32_bf16(kf, qf[ks], s[n], 0, 0, 0);
            }
        }
        __builtin_amdgcn_s_setprio(0);
        // ---- causal mask: only the diagonal tile needs it ----
        float sv[8][4];
#pragma unroll
        for (int n = 0; n < 8; ++n) {
            sv[n][0] = s[n][0]; sv[n][1] = s[n][1]; sv[n][2] = s[n][2]; sv[n][3] = s[n][3];
        }
        if (kb == nt - 1) {
#pragma unroll
            for (int n = 0; n < 8; ++n)
#pragma unroll
                for (int r = 0; r < 4; ++r) {
                    int kv = kb * 128 + n * 16 + hi * 4 + r;
                    if (kv > qrow) sv[n][r] = -3.0e38f;
                }
        }
        // ---- online softmax, log2 domain, defer-max (THR=8) ----
        float t8[8];
#pragma unroll
        for (int n = 0; n < 8; ++n)
            t8[n] = fmaxf(fmaxf(sv[n][0], sv[n][1]), fmaxf(sv[n][2], sv[n][3]));
        float mx = fmaxf(fmaxf(fmaxf(t8[0], t8[1]), fmaxf(t8[2], t8[3])),
                         fmaxf(fmaxf(t8[4], t8[5]), fmaxf(t8[6], t8[7])));
        mx = fmaxf(mx, __shfl_xor(mx, 16));
        mx = fmaxf(mx, __shfl_xor(mx, 32));
        float mxs = mx * SCL;
        if (!__all(mxs <= m_run + 8.0f)) {
            float mnew = fmaxf(m_run, mxs);
            float alpha = __builtin_amdgcn_exp2f(m_run - mnew);
            l_run *= alpha;
#pragma unroll
            for (int n2 = 0; n2 < 4; ++n2)
#pragma unroll
                for (int r = 0; r < 4; ++r) acc[n2][r] *= alpha;
            m_run = mnew;
        }
        float rs = 0.0f;
#pragma unroll
        for (int n = 0; n < 8; ++n) {
            float p0 = __builtin_amdgcn_exp2f(__builtin_fmaf(sv[n][0], SCL, -m_run));
            float p1 = __builtin_amdgcn_exp2f(__builtin_fmaf(sv[n][1], SCL, -m_run));
            float p2 = __builtin_amdgcn_exp2f(__builtin_fmaf(sv[n][2], SCL, -m_run));
            float p3 = __builtin_amdgcn_exp2f(__builtin_fmaf(sv[n][3], SCL, -m_run));
            sv[n][0] = p0; sv[n][1] = p1; sv[n][2] = p2; sv[n][3] = p3;
            rs += (p0 + p1) + (p2 + p3);
        }
        rs += __shfl_xor(rs, 16);
        rs += __shfl_xor(rs, 32);
        l_run += rs;

        // ---- pack P^T to bf16 pairs in-register ----
        unsigned pk0[8], pk1[8];
#pragma unroll
        for (int n = 0; n < 8; ++n) {
            pk0[n] = pack_bf16(sv[n][0], sv[n][1]);
            pk1[n] = pack_bf16(sv[n][2], sv[n][3]);
        }
        // ---- build B-fragments of P^T via cross-lane exchange, then PV ----
        int src0 = lr + ((hi & 1) << 5);
        int src1 = src0 + 16;
#pragma unroll
        for (int ks = 0; ks < 4; ++ks) {
            union { unsigned w4[4]; bf16x8 v; } pf;
            {
                unsigned a0 = __shfl(pk0[2 * ks], src0), b0 = __shfl(pk0[2 * ks + 1], src0);
                unsigned a1 = __shfl(pk1[2 * ks], src0), b1 = __shfl(pk1[2 * ks + 1], src0);
                unsigned a2 = __shfl(pk0[2 * ks], src1), b2 = __shfl(pk0[2 * ks + 1], src1);
                unsigned a3 = __shfl(pk1[2 * ks], src1), b3 = __shfl(pk1[2 * ks + 1], src1);
                pf.w4[0] = upper ? b0 : a0;
                pf.w4[1] = upper ? b1 : a1;
                pf.w4[2] = upper ? b2 : a2;
                pf.w4[3] = upper ? b3 : a3;
            }
            __builtin_amdgcn_s_setprio(1);
#pragma unroll
            for (int n2 = 0; n2 < 4; ++n2) {
                bf16x8 vf = *reinterpret_cast<const bf16x8*>(&vtb[swz128(n2 * 16 + lr, ks * 32 + hi * 8)]);
                acc[n2] = __builtin_amdgcn_mfma_f32_16x16x32_bf16(vf, pf.v, acc[n2], 0, 0, 0);
            }
            __builtin_amdgcn_s_setprio(0);
        }
        if (kb + 1 < nt) WRITEKV((kb + 1) & 1);
    }
    // ---- store O^T -> attn[q][h*64+d], normalized ----
    float inv = 1.0f / l_run;
#pragma unroll
    for (int n2 = 0; n2 < 4; ++n2) {
#pragma unroll
        for (int r = 0; r < 4; ++r) {
            int dcol = h * 64 + n2 * 16 + hi * 4 + r;
            attn[(size_t)qrow * DM + dcol] = f2bf(acc[n2][r] * inv);
        }
    }
}

extern "C" void kernel_launch(void* const* d_in, const int* in_sizes, int n_in,
                              void* d_out, int out_size, void* d_ws, size_t ws_size,
                              hipStream_t stream) {
    const float* x      = (const float*)d_in[0];
    const float* gamma1 = (const float*)d_in[1];
    const float* beta1  = (const float*)d_in[2];
    const float* Wqkv   = (const float*)d_in[3];
    const float* bqkv   = (const float*)d_in[4];
    const float* Wo     = (const float*)d_in[5];
    const float* bo     = (const float*)d_in[6];
    const float* gamma2 = (const float*)d_in[7];
    const float* beta2  = (const float*)d_in[8];
    const float* W1     = (const float*)d_in[9];
    const float* b1     = (const float*)d_in[10];
    const float* W2     = (const float*)d_in[11];
    const float* b2     = (const float*)d_in[12];

    char* ws = (char*)d_ws;
    size_t off = 0;
    u16* WqkvT = (u16*)(ws + off); off += (size_t)2304 * 768 * 2;
    u16* WoT   = (u16*)(ws + off); off += (size_t)768 * 768 * 2;
    u16* W1T   = (u16*)(ws + off); off += (size_t)3072 * 768 * 2;
    u16* W2T   = (u16*)(ws + off); off += (size_t)768 * 3072 * 2;
    u16* B1    = (u16*)(ws + off); off += (size_t)SEQ * DM * 2;      // y1 / attn / y2
    u16* Q     = (u16*)(ws + off); off += (size_t)SEQ * HID * 2;     // qkv, then h
    float* x1  = (float*)(ws + off); off += (size_t)SEQ * DM * 4;

    // VtG [NH][64][SEQ] lives in x1's region (dead until the Wo GEMM writes it)
    u16* VtG = (u16*)x1;

    prep_kernel<<<dim3(11008), 256, 0, stream>>>(x, gamma1, beta1, Wqkv, Wo, W1, W2,
                                                 WqkvT, WoT, W1T, W2T, B1);
    // QKV: 1D grid 18*64=1152 (div by 8), writes V transposed to VtG in epilogue
    gemm_bf16<64, 128><<<dim3(1152), 256, 0, stream>>>(B1, WqkvT, bqkv, nullptr, nullptr, Q, VtG, SEQ, 2304, 768, 0);
    attn_kernel<<<dim3((SEQ / 64) * NH), 256, 0, stream>>>(Q, VtG, B1);
    gemm_bf16<64, 64><<<dim3(768), 256, 0, stream>>>(B1, WoT, bo, x, x1, nullptr, nullptr, SEQ, 768, 768, 0);
    ln_kernel<<<SEQ, 256, 0, stream>>>(x1, gamma2, beta2, B1);
    gemm_bf16<64, 128><<<dim3(1536), 256, 0, stream>>>(B1, W1T, b1, nullptr, nullptr, Q, nullptr, SEQ, 3072, 768, 1);
    gemm_bf16<64, 64><<<dim3(768), 256, 0, stream>>>(Q, W2T, b2, x1, (float*)d_out, nullptr, nullptr, SEQ, 768, 3072, 0);
}